// Round 11
// baseline (116.998 us; speedup 1.0000x reference)
//
#include <hip/hip_runtime.h>
#include <hip/hip_bf16.h>
#include <cstdint>

#define BATCH 16
#define TTOT  4096
#define DIN   512
#define DOUT  512
#define NG    8
#define NJOB  33
#define NKT   16     // K tiles of 32

typedef float f32x4 __attribute__((ext_vector_type(4)));
typedef short s16x8 __attribute__((ext_vector_type(8)));

__device__ __forceinline__ short f2b(float f) {
    union { __bf16 b; short s; } u; u.b = (__bf16)f; return u.s;
}

// M-tile jobs per batch (BM=128): 31 full + two 64-row stubs (proven R3/R5).
__device__ __constant__ short JT0[NJOB] = {
    0,128, 256,384,512,640, 768,896,1024,1152,1280,1408, 1536,1664,1792,
    1920,2048,2176,2304,2432, 2560,2688,2816,2944, 3072,3200,3328,3456,
    3584, 3648, 3712,3840,3968};
__device__ __constant__ char JG[NJOB] = {
    0,0, 1,1,1,1, 2,2,2,2,2,2, 3,3,3, 4,4,4,4,4, 5,5,5,5, 6,6,6,6, 6, 7, 7,7,7};
__device__ __constant__ char JBM[NJOB] = {
    127,127, 127,127,127,127, 127,127,127,127,127,127, 127,127,127,
    127,127,127,127,127, 127,127,127,127, 127,127,127,127, 63, 63, 127,127,127};

// ---- Kernel 1: W fp32 -> bf16 slot-swizzled LDS-image chunks (BK=32) ----
// chunk c = ((g*4+nt)<<4)|kt, 8KB: img[r<128][slot<4 (16B)] holds source slot
// (slot ^ s(r)), s(r)=(r>>1)&3:  k = kt*32 + ((slot^s(r))<<3) + 0..7
__global__ void wconv_kernel(const float* __restrict__ W, ushort* __restrict__ wbf) {
    int gid = blockIdx.x * 256 + threadIdx.x;   // 262144 granules x 16B
    int c = gid >> 9;                           // 512 granules / 8KB chunk
    int q = (gid & 511) << 4;
    int r = q >> 6;                             // 0..127
    int slot = (q >> 4) & 3;
    int kt = c & 15, nt = (c >> 4) & 3, g = c >> 6;
    int k = (kt << 5) + (((slot ^ ((r >> 1) & 3))) << 3);
    const float* wp = W + ((size_t)((g << 9) + (nt << 7) + r) << 9) + k;
    float4 v0 = *reinterpret_cast<const float4*>(wp);
    float4 v1 = *reinterpret_cast<const float4*>(wp + 4);
    s16x8 o;
    o[0]=f2b(v0.x); o[1]=f2b(v0.y); o[2]=f2b(v0.z); o[3]=f2b(v0.w);
    o[4]=f2b(v1.x); o[5]=f2b(v1.y); o[6]=f2b(v1.z); o[7]=f2b(v1.w);
    *reinterpret_cast<s16x8*>((char*)wbf + (size_t)c * 8192 + q) = o;
}

// ---- Kernel 2: grouped GEMM 128x128x32, 4 waves (2Mx2N), wave 64x64.
// LDS 32KB -> 4 blocks/CU (16 waves/CU). Counted vmcnt: A(kt+2) rides
// every barrier; B(kt+1) drained by vmcnt(4). ----
__launch_bounds__(256, 4)
__global__ void gemm_kernel(const float* __restrict__ x,
                            const ushort* __restrict__ wbf,
                            const float* __restrict__ bias,
                            float* __restrict__ out) {
    // [A0 8K][A1 8K][B0 8K][B1 8K]; epilogue cbuf (32x132 f32) overlays.
    __shared__ __align__(16) char smem[32768];

    const int tid  = threadIdx.x;
    const int lane = tid & 63;
    const int wv   = tid >> 6;      // 0..3
    const int wm   = wv >> 1;       // 0..1 : 64-row slab
    const int wn   = wv & 1;        // 0..1 : 64-col slab
    const int colf = lane & 15;
    const int kg   = lane >> 4;

    const int p    = blockIdx.x;
    const int l    = (p & 7) * 264 + (p >> 3);   // XCD-chunked (2112 = 8*264)
    const int nt   = l & 3;                       // nt fastest: x L2/L3 reuse
    const int rest = l >> 2;                      // 0..527
    const int job  = rest >> 4;                   // 0..32
    const int bb   = rest & 15;
    const int t0   = JT0[job];
    const int g    = JG[job];
    const int bmm1 = JBM[job];
    const int n0   = nt << 7;

    const char* bchunk = (const char*)wbf + ((size_t)(((g << 2) + nt) << 4)) * 8192;

    // A staging: thread -> row r = tid>>1 (0..127), half h = tid&1 (16 f32)
    const int r = tid >> 1;
    const int h = tid & 1;
    const int re = (r <= bmm1) ? r : bmm1;
    const float* aptr = x + ((size_t)(bb * TTOT + t0 + re) << 9) + (h << 4);
    // A LDS write offsets for the 2 source slots (h*2+j), swizzled:
    const int sr = (r >> 1) & 3;
    const int aw0 = (r << 6) + ((((h << 1) | 0) ^ sr) << 4);
    const int aw1 = (r << 6) + ((((h << 1) | 1) ^ sr) << 4);

    float4 aE[4], aO[4];

#define ISSUE_A(S, KT_) do {                                                \
        const float* p_ = aptr + ((KT_) << 5);                              \
        a##S[0] = *(const float4*)(p_);                                     \
        a##S[1] = *(const float4*)(p_ + 4);                                 \
        a##S[2] = *(const float4*)(p_ + 8);                                 \
        a##S[3] = *(const float4*)(p_ + 12);                                \
    } while (0)

#define CVT_WRITE_A(S, KT_) do {                                            \
        char* ab_ = smem + (((KT_) & 1) << 13);                             \
        s16x8 o0_, o1_;                                                     \
        o0_[0]=f2b(a##S[0].x); o0_[1]=f2b(a##S[0].y);                       \
        o0_[2]=f2b(a##S[0].z); o0_[3]=f2b(a##S[0].w);                       \
        o0_[4]=f2b(a##S[1].x); o0_[5]=f2b(a##S[1].y);                       \
        o0_[6]=f2b(a##S[1].z); o0_[7]=f2b(a##S[1].w);                       \
        o1_[0]=f2b(a##S[2].x); o1_[1]=f2b(a##S[2].y);                       \
        o1_[2]=f2b(a##S[2].z); o1_[3]=f2b(a##S[2].w);                       \
        o1_[4]=f2b(a##S[3].x); o1_[5]=f2b(a##S[3].y);                       \
        o1_[6]=f2b(a##S[3].z); o1_[7]=f2b(a##S[3].w);                       \
        *(s16x8*)(ab_ + aw0) = o0_;                                         \
        *(s16x8*)(ab_ + aw1) = o1_;                                         \
    } while (0)

#define ISSUE_B(KT_) do {                                                   \
        const char* s_ = bchunk + ((size_t)(KT_) << 13) + tid * 16;         \
        char* d_ = smem + 16384 + (((KT_) & 1) << 13) + tid * 16;           \
        __builtin_amdgcn_global_load_lds(                                   \
            (const __attribute__((address_space(1))) void*)(s_),            \
            (__attribute__((address_space(3))) void*)(d_), 16, 0, 0);       \
        __builtin_amdgcn_global_load_lds(                                   \
            (const __attribute__((address_space(1))) void*)(s_ + 4096),     \
            (__attribute__((address_space(3))) void*)(d_ + 4096), 16, 0, 0);\
    } while (0)

#define COMPUTE(KT_) do {                                                   \
        const char* ab_ = smem + (((KT_) & 1) << 13);                       \
        const char* bb_ = smem + 16384 + (((KT_) & 1) << 13);               \
        __builtin_amdgcn_s_setprio(1);                                      \
        s16x8 bf[4];                                                        \
        _Pragma("unroll")                                                   \
        for (int ni = 0; ni < 4; ++ni) {                                    \
            int r_ = wn * 64 + ni * 16 + colf;                              \
            bf[ni] = *(const s16x8*)(bb_ + (r_ << 6)                        \
                        + (((kg ^ ((r_ >> 1) & 3))) << 4));                 \
        }                                                                   \
        _Pragma("unroll")                                                   \
        for (int mi = 0; mi < 4; ++mi) {                                    \
            int r_ = wm * 64 + mi * 16 + colf;                              \
            s16x8 af = *(const s16x8*)(ab_ + (r_ << 6)                      \
                        + (((kg ^ ((r_ >> 1) & 3))) << 4));                 \
            _Pragma("unroll")                                               \
            for (int ni = 0; ni < 4; ++ni)                                  \
                acc[mi][ni] = __builtin_amdgcn_mfma_f32_16x16x32_bf16(      \
                    af, bf[ni], acc[mi][ni], 0, 0, 0);                      \
        }                                                                   \
        __builtin_amdgcn_s_setprio(0);                                      \
    } while (0)

#define FENCE  asm volatile("" ::: "memory")
#define WAITV4 asm volatile("s_waitcnt vmcnt(4)" ::: "memory")
#define WAITV0 asm volatile("s_waitcnt vmcnt(0)" ::: "memory")
#define WAITL0 asm volatile("s_waitcnt lgkmcnt(0)" ::: "memory")
#define BAR    __builtin_amdgcn_s_barrier()

    f32x4 acc[4][4];
#pragma unroll
    for (int mi = 0; mi < 4; ++mi)
#pragma unroll
        for (int ni = 0; ni < 4; ++ni)
            acc[mi][ni] = (f32x4){0.f, 0.f, 0.f, 0.f};

    // ---- prologue: A(0),B(0) staged; A(1) in flight ----
    ISSUE_A(E, 0);
    FENCE;
    ISSUE_B(0);
    FENCE;
    ISSUE_A(O, 1);
    FENCE;
    CVT_WRITE_A(E, 0);   // reg-dep: vmcnt(6) -> A(0) landed, B(0)+A(1) fly
    WAITV4;              // drain B(0); A(1) rides
    WAITL0;
    BAR;

#pragma unroll
    for (int kt = 0; kt < NKT; ++kt) {
        if (kt + 1 < NKT) { ISSUE_B(kt + 1); FENCE; }
        if (kt + 2 < NKT) {
            if (((kt + 2) & 1) == 0) { ISSUE_A(E, kt + 2); }
            else                     { ISSUE_A(O, kt + 2); }
            FENCE;
        }
        COMPUTE(kt);
        if (kt + 1 < NKT) {
            if (((kt + 1) & 1) == 0) { CVT_WRITE_A(E, kt + 1); }
            else                     { CVT_WRITE_A(O, kt + 1); }
            if (kt + 2 < NKT) { WAITV4; }   // drain B(kt+1); A(kt+2) rides
            else              { WAITV0; }   // kt==14: only B(15) left
            WAITL0;
            BAR;
        }
    }
    BAR;   // all LDS reads done before cbuf overlay

    // ---- epilogue: 4 passes of 32 rows via LDS transpose (stride 132) ----
    float* cbuf = (float*)smem;            // 32*132*4 = 16.9KB
    const int er = tid >> 3;               // 0..31
    const int ec = (tid & 7) << 4;         // 16 f32 per thread
    float4 bvv[4];
#pragma unroll
    for (int i = 0; i < 4; ++i)
        bvv[i] = *(const float4*)(bias + (g << 9) + n0 + ec + (i << 2));

#pragma unroll
    for (int pp = 0; pp < 4; ++pp) {
        if (wm == (pp >> 1)) {
#pragma unroll
            for (int m = 0; m < 2; ++m) {
                const int mi = (pp & 1) * 2 + m;
#pragma unroll
                for (int ni = 0; ni < 4; ++ni) {
                    const int base = (m * 16 + kg * 4) * 132 + wn * 64 + ni * 16 + colf;
                    f32x4 v = acc[mi][ni];
                    cbuf[base]       = v[0];
                    cbuf[base + 132] = v[1];
                    cbuf[base + 264] = v[2];
                    cbuf[base + 396] = v[3];
                }
            }
        }
        WAITL0;
        BAR;
        const int row = pp * 32 + er;
        if (row <= bmm1) {
            float* orow = out + ((size_t)(bb * TTOT + t0 + row) << 9) + n0 + ec;
            const float* crow = cbuf + er * 132 + ec;
#pragma unroll
            for (int i = 0; i < 4; ++i) {
                float4 v = *(const float4*)(crow + (i << 2));
                float4 o4;
                o4.x = v.x + bvv[i].x; o4.y = v.y + bvv[i].y;
                o4.z = v.z + bvv[i].z; o4.w = v.w + bvv[i].w;
                *(float4*)(orow + (i << 2)) = o4;
            }
        }
        BAR;
    }
#undef ISSUE_A
#undef CVT_WRITE_A
#undef ISSUE_B
#undef COMPUTE
#undef FENCE
#undef WAITV4
#undef WAITV0
#undef WAITL0
#undef BAR
}

// ---- Fallback (ws too small): R2-style 64x128 kernel, fp32 W path ----
__launch_bounds__(256)
__global__ void gemm_fallback(const float* __restrict__ x,
                              const float* __restrict__ W,
                              const float* __restrict__ bias,
                              float* __restrict__ out) {
    __shared__ __align__(16) char smem[49152];
    const int tid  = threadIdx.x;
    const int lane = tid & 63;
    const int wid  = tid >> 6;
    const int wm   = wid >> 1;
    const int wn   = wid & 1;
    const int p  = blockIdx.x;
    const int l  = ((p & 7) << 9) + (p >> 3);
    const int mt = l >> 2;
    const int nt = l & 3;
    const int bb = mt >> 6;
    const int t0 = (mt & 63) << 6;
    const int n0 = nt << 7;
    int g = 0;
    if (t0 >= 256)  g++; if (t0 >= 768)  g++; if (t0 >= 1536) g++;
    if (t0 >= 1920) g++; if (t0 >= 2560) g++; if (t0 >= 3072) g++;
    if (t0 >= 3648) g++;
    const int arow = tid >> 2;
    const int acol = (tid & 3) << 4;
    const float* aptr = x + ((size_t)(bb * TTOT + t0 + arow)) * DIN + acol;
    float4 a0, a1, a2, a3;
    float4 bw0[4], bw1[4];
    auto load_global = [&](int k0) {
        a0 = *(const float4*)(aptr + k0);
        a1 = *(const float4*)(aptr + k0 + 4);
        a2 = *(const float4*)(aptr + k0 + 8);
        a3 = *(const float4*)(aptr + k0 + 12);
#pragma unroll
        for (int pp = 0; pp < 4; ++pp) {
            int idx = pp * 256 + tid;
            int row = idx >> 3, seg = idx & 7;
            const float* wp = W + ((size_t)((g << 9) + n0 + row)) * DIN + k0 + (seg << 3);
            bw0[pp] = *(const float4*)(wp);
            bw1[pp] = *(const float4*)(wp + 4);
        }
    };
    auto swzf = [](int row, int bc) { return (row << 7) + (bc ^ ((row & 7) << 4)); };
    auto write_lds = [&](int buf) {
        char* ab  = smem + buf * 8192;
        char* bb_ = smem + 16384 + buf * 16384;
        s16x8 w0, w1;
        w0[0]=f2b(a0.x); w0[1]=f2b(a0.y); w0[2]=f2b(a0.z); w0[3]=f2b(a0.w);
        w0[4]=f2b(a1.x); w0[5]=f2b(a1.y); w0[6]=f2b(a1.z); w0[7]=f2b(a1.w);
        w1[0]=f2b(a2.x); w1[1]=f2b(a2.y); w1[2]=f2b(a2.z); w1[3]=f2b(a2.w);
        w1[4]=f2b(a3.x); w1[5]=f2b(a3.y); w1[6]=f2b(a3.z); w1[7]=f2b(a3.w);
        const int abase2 = acol << 1;
        *(s16x8*)(ab + swzf(arow, abase2))      = w0;
        *(s16x8*)(ab + swzf(arow, abase2 + 16)) = w1;
#pragma unroll
        for (int pp = 0; pp < 4; ++pp) {
            int idx = pp * 256 + tid;
            int row = idx >> 3, seg = idx & 7;
            s16x8 wvv;
            wvv[0]=f2b(bw0[pp].x); wvv[1]=f2b(bw0[pp].y);
            wvv[2]=f2b(bw0[pp].z); wvv[3]=f2b(bw0[pp].w);
            wvv[4]=f2b(bw1[pp].x); wvv[5]=f2b(bw1[pp].y);
            wvv[6]=f2b(bw1[pp].z); wvv[7]=f2b(bw1[pp].w);
            *(s16x8*)(bb_ + swzf(row, seg << 4)) = wvv;
        }
    };
    f32x4 acc[2][4];
#pragma unroll
    for (int mi = 0; mi < 2; ++mi)
#pragma unroll
        for (int ni = 0; ni < 4; ++ni) acc[mi][ni] = (f32x4){0.f,0.f,0.f,0.f};
    const int colf = lane & 15;
    const int kgrp = lane >> 4;
    auto compute = [&](int buf) {
        const char* ab  = smem + buf * 8192;
        const char* bb_ = smem + 16384 + buf * 16384;
#pragma unroll
        for (int ks = 0; ks < 2; ++ks) {
            const int kb = ks * 64 + kgrp * 16;
            s16x8 af[2], bf[4];
#pragma unroll
            for (int mi = 0; mi < 2; ++mi)
                af[mi] = *(const s16x8*)(ab + swzf(wm * 32 + mi * 16 + colf, kb));
#pragma unroll
            for (int ni = 0; ni < 4; ++ni)
                bf[ni] = *(const s16x8*)(bb_ + swzf(wn * 64 + ni * 16 + colf, kb));
#pragma unroll
            for (int mi = 0; mi < 2; ++mi)
#pragma unroll
                for (int ni = 0; ni < 4; ++ni)
                    acc[mi][ni] = __builtin_amdgcn_mfma_f32_16x16x32_bf16(
                        af[mi], bf[ni], acc[mi][ni], 0, 0, 0);
        }
    };
    load_global(0);
    write_lds(0);
    __syncthreads();
    int buf = 0;
#pragma unroll 1
    for (int kt = 0; kt < 8; ++kt) {
        if (kt < 7) load_global((kt + 1) << 6);
        compute(buf);
        if (kt < 7) write_lds(buf ^ 1);
        __syncthreads();
        buf ^= 1;
    }
    float* cbuf = (float*)smem;
#pragma unroll
    for (int ni = 0; ni < 4; ++ni) {
        const int c = wn * 64 + ni * 16 + colf;
#pragma unroll
        for (int mi = 0; mi < 2; ++mi) {
            const int rr2 = wm * 32 + mi * 16 + kgrp * 4;
            f32x4 v = acc[mi][ni];
            cbuf[(rr2 + 0) * 132 + c] = v[0];
            cbuf[(rr2 + 1) * 132 + c] = v[1];
            cbuf[(rr2 + 2) * 132 + c] = v[2];
            cbuf[(rr2 + 3) * 132 + c] = v[3];
        }
    }
    __syncthreads();
    const int rr = tid >> 5;
    const int cc = (tid & 31) << 2;
    const float4 bvv = *(const float4*)(bias + (g << 9) + n0 + cc);
#pragma unroll
    for (int it = 0; it < 8; ++it) {
        const int row = it * 8 + rr;
        float4 v = *(const float4*)(cbuf + row * 132 + cc);
        float4 o4; o4.x = v.x + bvv.x; o4.y = v.y + bvv.y;
                   o4.z = v.z + bvv.z; o4.w = v.w + bvv.w;
        *(float4*)(out + ((size_t)(bb * TTOT) + t0 + row) * DOUT + n0 + cc) = o4;
    }
}

extern "C" void kernel_launch(void* const* d_in, const int* in_sizes, int n_in,
                              void* d_out, int out_size, void* d_ws, size_t ws_size,
                              hipStream_t stream) {
    const float* x    = (const float*)d_in[0];
    const float* W    = (const float*)d_in[1];
    const float* bias = (const float*)d_in[2];
    float* out = (float*)d_out;

    const size_t wbytes = (size_t)NG * DOUT * DIN * sizeof(ushort);  // 4 MB

    if (ws_size >= wbytes) {
        ushort* wbf = (ushort*)d_ws;
        wconv_kernel<<<1024, 256, 0, stream>>>(W, wbf);
        gemm_kernel<<<NJOB * BATCH * 4, 256, 0, stream>>>(x, wbf, bias, out);
    } else {
        gemm_fallback<<<BATCH * 64 * 4, 256, 0, stream>>>(x, W, bias, out);
    }
}

// Round 12
// 102.520 us; speedup vs baseline: 1.1412x; 1.1412x over previous
//
#include <hip/hip_runtime.h>
#include <hip/hip_bf16.h>
#include <cstdint>

#define BATCH 16
#define TTOT  4096
#define DIN   512
#define DOUT  512
#define NG    8
#define NJOB  33
#define NKT   8      // K tiles of 64

typedef float f32x4 __attribute__((ext_vector_type(4)));
typedef short s16x8 __attribute__((ext_vector_type(8)));

__device__ __forceinline__ short f2b(float f) {
    union { __bf16 b; short s; } u; u.b = (__bf16)f; return u.s;
}

// M-tile jobs per batch (BM=128): 31 full + two 64-row stubs (proven R3/R5).
__device__ __constant__ short JT0[NJOB] = {
    0,128, 256,384,512,640, 768,896,1024,1152,1280,1408, 1536,1664,1792,
    1920,2048,2176,2304,2432, 2560,2688,2816,2944, 3072,3200,3328,3456,
    3584, 3648, 3712,3840,3968};
__device__ __constant__ char JG[NJOB] = {
    0,0, 1,1,1,1, 2,2,2,2,2,2, 3,3,3, 4,4,4,4,4, 5,5,5,5, 6,6,6,6, 6, 7, 7,7,7};
__device__ __constant__ char JBM[NJOB] = {
    127,127, 127,127,127,127, 127,127,127,127,127,127, 127,127,127,
    127,127,127,127,127, 127,127,127,127, 127,127,127,127, 63, 63, 127,127,127};

// ---- Kernel 1: W fp32 -> bf16 FRAGMENT-MAJOR image ----
// granule gid (16B): lane l = gid&63; u=gid>>6: ks=u&1, ni=(u>>1)&3,
// wn=(u>>3)&1, kt=(u>>4)&7, nt=(u>>7)&3, g=u>>9.
// element: row = nt*128+wn*64+ni*16+(l&15), k = kt*64+ks*32+(l>>4)*8 .. +7
__global__ void wconv_kernel(const float* __restrict__ W, ushort* __restrict__ wbf) {
    int gid = blockIdx.x * 256 + threadIdx.x;   // 262144 granules x 16B
    int l  = gid & 63;
    int u  = gid >> 6;
    int ks = u & 1;
    int ni = (u >> 1) & 3;
    int wn = (u >> 3) & 1;
    int kt = (u >> 4) & 7;
    int nt = (u >> 7) & 3;
    int g  = u >> 9;
    int row = nt * 128 + wn * 64 + ni * 16 + (l & 15);
    int k   = kt * 64 + ks * 32 + (l >> 4) * 8;
    const float* wp = W + ((size_t)(g * DOUT + row)) * DIN + k;
    float4 v0 = *reinterpret_cast<const float4*>(wp);
    float4 v1 = *reinterpret_cast<const float4*>(wp + 4);
    s16x8 o;
    o[0]=f2b(v0.x); o[1]=f2b(v0.y); o[2]=f2b(v0.z); o[3]=f2b(v0.w);
    o[4]=f2b(v1.x); o[5]=f2b(v1.y); o[6]=f2b(v1.z); o[7]=f2b(v1.w);
    *reinterpret_cast<s16x8*>((char*)wbf + (size_t)gid * 16) = o;
}

// ---- Kernel 2: grouped GEMM 128x128x64, 4 waves (2Mx2N), wave 64x64.
// A: reg-staged 2-deep -> swizzled LDS dbuf (R5-proven). B: DIRECT global->
// register MFMA fragments (1KB coalesced per wave-instr), 1-iter prefetch.
// One barrier per K-iter (A dbuf only, lgkmcnt(0)); NO vmcnt drains. ----
__launch_bounds__(256, 2)
__global__ void gemm_kernel(const float* __restrict__ x,
                            const ushort* __restrict__ wbf,
                            const float* __restrict__ bias,
                            float* __restrict__ out) {
    // [A0 16K][A1 16K]; epilogue cbuf (32x132 f32 = 16.9K) overlays A0.
    __shared__ __align__(16) char smem[32768];

    const int tid  = threadIdx.x;
    const int lane = tid & 63;
    const int wv   = tid >> 6;      // 0..3
    const int wm   = wv >> 1;       // 0..1 : 64-row slab
    const int wn   = wv & 1;        // 0..1 : 64-col slab
    const int colf = lane & 15;
    const int kg   = lane >> 4;

    const int p    = blockIdx.x;
    const int l    = (p & 7) * 264 + (p >> 3);   // XCD-chunked (2112 = 8*264)
    const int nt   = l & 3;                       // nt fastest: x L2 reuse
    const int rest = l >> 2;                      // 0..527
    const int job  = rest >> 4;                   // 0..32
    const int bb   = rest & 15;
    const int t0   = JT0[job];
    const int g    = JG[job];
    const int bmm1 = JBM[job];
    const int n0   = nt << 7;

    // B fragment base for this block's (g,nt,wn): per kt 16KB; per (ni,ks) 1KB
    const char* bfbase = (const char*)wbf
        + ((size_t)((g * 4 + nt) * 8)) * 16384 + (wn ? 8192 : 0) + lane * 16;

    // A staging (R5 geometry): wave wv stages rows wv*32..+31; per j: row =
    // wv*32 + (lane>>3) + j*8, two float4 at fp32 cols (lane&7)*8, +4.
    const int arow_s = (wv << 5) + (lane >> 3);
    const int col8   = (lane & 7) << 3;
    const float* aptr = x + ((size_t)(bb * TTOT + t0 + arow_s)) * DIN + col8;

    float4 stE[4][2], stO[4][2];
    s16x8 bE[8], bO[8];

#define ISSUE_A(S, KT_) do {                                                \
        _Pragma("unroll")                                                   \
        for (int j_ = 0; j_ < 4; ++j_) {                                    \
            const float* p_ = aptr + (size_t)(j_ * 8) * DIN + ((KT_) << 6); \
            st##S[j_][0] = *(const float4*)(p_);                            \
            st##S[j_][1] = *(const float4*)(p_ + 4);                        \
        }                                                                   \
    } while (0)

#define CVT_WRITE_A(S, KT_) do {                                            \
        char* ab_ = smem + (((KT_) & 1) << 14);                             \
        _Pragma("unroll")                                                   \
        for (int j_ = 0; j_ < 4; ++j_) {                                    \
            float4 lo_ = st##S[j_][0], hi_ = st##S[j_][1];                  \
            s16x8 o_;                                                       \
            o_[0]=f2b(lo_.x); o_[1]=f2b(lo_.y); o_[2]=f2b(lo_.z); o_[3]=f2b(lo_.w); \
            o_[4]=f2b(hi_.x); o_[5]=f2b(hi_.y); o_[6]=f2b(hi_.z); o_[7]=f2b(hi_.w); \
            int row_ = arow_s + j_ * 8;                                     \
            int bc_ = (col8 << 1) ^ ((row_ & 7) << 4);                      \
            *(s16x8*)(ab_ + (row_ << 7) + bc_) = o_;                        \
        }                                                                   \
    } while (0)

#define ISSUE_BF(S, KT_) do {                                               \
        const char* b_ = bfbase + ((size_t)(KT_) << 14);                    \
        _Pragma("unroll")                                                   \
        for (int q_ = 0; q_ < 8; ++q_)                                      \
            b##S[q_] = *(const s16x8*)(b_ + q_ * 1024);                     \
    } while (0)

#define COMPUTE(S, KT_) do {                                                \
        const char* ab_ = smem + (((KT_) & 1) << 14);                       \
        _Pragma("unroll")                                                   \
        for (int ks = 0; ks < 2; ++ks) {                                    \
            const int kb = ks * 64 + (kg << 4);                             \
            s16x8 af[4];                                                    \
            _Pragma("unroll")                                               \
            for (int mi = 0; mi < 4; ++mi) {                                \
                int r_ = wm * 64 + mi * 16 + colf;                          \
                af[mi] = *(const s16x8*)(ab_ + (r_ << 7) + (kb ^ ((r_ & 7) << 4))); \
            }                                                               \
            _Pragma("unroll")                                               \
            for (int mi = 0; mi < 4; ++mi)                                  \
                _Pragma("unroll")                                           \
                for (int ni = 0; ni < 4; ++ni)                              \
                    acc[mi][ni] = __builtin_amdgcn_mfma_f32_16x16x32_bf16(  \
                        af[mi], b##S[ni * 2 + ks], acc[mi][ni], 0, 0, 0);   \
        }                                                                   \
    } while (0)

#define FENCE  asm volatile("" ::: "memory")
#define WAITL0 asm volatile("s_waitcnt lgkmcnt(0)" ::: "memory")
#define BAR    __builtin_amdgcn_s_barrier()

    f32x4 acc[4][4];
#pragma unroll
    for (int mi = 0; mi < 4; ++mi)
#pragma unroll
        for (int ni = 0; ni < 4; ++ni)
            acc[mi][ni] = (f32x4){0.f, 0.f, 0.f, 0.f};

    // ---- prologue ----
    ISSUE_BF(E, 0);      // B(0) frags in flight
    ISSUE_A(E, 0);
    FENCE;
    ISSUE_A(O, 1);
    FENCE;
    CVT_WRITE_A(E, 0);   // reg-dep waits A(0); B(0)+A(1) keep flying
    WAITL0;
    BAR;

#pragma unroll
    for (int kt = 0; kt < NKT; ++kt) {
        if (kt + 1 < NKT) {
            if (((kt + 1) & 1) == 0) { ISSUE_BF(E, kt + 1); }
            else                     { ISSUE_BF(O, kt + 1); }
            FENCE;
        }
        if (kt + 2 < NKT) {
            if (((kt + 2) & 1) == 0) { ISSUE_A(E, kt + 2); }
            else                     { ISSUE_A(O, kt + 2); }
            FENCE;
        }
        if ((kt & 1) == 0) { COMPUTE(E, kt); } else { COMPUTE(O, kt); }
        if (kt + 1 < NKT) {
            if (((kt + 1) & 1) == 0) { CVT_WRITE_A(E, kt + 1); }
            else                     { CVT_WRITE_A(O, kt + 1); }
            WAITL0;
            BAR;
        }
    }
    BAR;   // all LDS reads done before cbuf overlay

    // ---- epilogue: 4 passes of 32 rows via LDS transpose (stride 132) ----
    float* cbuf = (float*)smem;            // 32*132*4 = 16.9KB (A region)
    const int er = tid >> 3;               // 0..31
    const int ec = (tid & 7) << 4;         // 16 f32 per thread
    float4 bvv[4];
#pragma unroll
    for (int i = 0; i < 4; ++i)
        bvv[i] = *(const float4*)(bias + (g << 9) + n0 + ec + (i << 2));

#pragma unroll
    for (int pp = 0; pp < 4; ++pp) {
        if (wm == (pp >> 1)) {
#pragma unroll
            for (int m = 0; m < 2; ++m) {
                const int mi = (pp & 1) * 2 + m;
#pragma unroll
                for (int ni = 0; ni < 4; ++ni) {
                    const int base = (m * 16 + kg * 4) * 132 + wn * 64 + ni * 16 + colf;
                    f32x4 v = acc[mi][ni];
                    cbuf[base]       = v[0];
                    cbuf[base + 132] = v[1];
                    cbuf[base + 264] = v[2];
                    cbuf[base + 396] = v[3];
                }
            }
        }
        WAITL0;
        BAR;
        const int row = pp * 32 + er;
        if (row <= bmm1) {
            float* orow = out + ((size_t)(bb * TTOT + t0 + row)) * DOUT + n0 + ec;
            const float* crow = cbuf + er * 132 + ec;
#pragma unroll
            for (int i = 0; i < 4; ++i) {
                float4 v = *(const float4*)(crow + (i << 2));
                float4 o4;
                o4.x = v.x + bvv[i].x; o4.y = v.y + bvv[i].y;
                o4.z = v.z + bvv[i].z; o4.w = v.w + bvv[i].w;
                *(float4*)(orow + (i << 2)) = o4;
            }
        }
        BAR;
    }
#undef ISSUE_A
#undef CVT_WRITE_A
#undef ISSUE_BF
#undef COMPUTE
#undef FENCE
#undef WAITL0
#undef BAR
}

// ---- Fallback (ws too small): R2-style 64x128 kernel, fp32 W path ----
__launch_bounds__(256)
__global__ void gemm_fallback(const float* __restrict__ x,
                              const float* __restrict__ W,
                              const float* __restrict__ bias,
                              float* __restrict__ out) {
    __shared__ __align__(16) char smem[49152];
    const int tid  = threadIdx.x;
    const int lane = tid & 63;
    const int wid  = tid >> 6;
    const int wm   = wid >> 1;
    const int wn   = wid & 1;
    const int p  = blockIdx.x;
    const int l  = ((p & 7) << 9) + (p >> 3);
    const int mt = l >> 2;
    const int nt = l & 3;
    const int bb = mt >> 6;
    const int t0 = (mt & 63) << 6;
    const int n0 = nt << 7;
    int g = 0;
    if (t0 >= 256)  g++; if (t0 >= 768)  g++; if (t0 >= 1536) g++;
    if (t0 >= 1920) g++; if (t0 >= 2560) g++; if (t0 >= 3072) g++;
    if (t0 >= 3648) g++;
    const int arow = tid >> 2;
    const int acol = (tid & 3) << 4;
    const float* aptr = x + ((size_t)(bb * TTOT + t0 + arow)) * DIN + acol;
    float4 a0, a1, a2, a3;
    float4 bw0[4], bw1[4];
    auto load_global = [&](int k0) {
        a0 = *(const float4*)(aptr + k0);
        a1 = *(const float4*)(aptr + k0 + 4);
        a2 = *(const float4*)(aptr + k0 + 8);
        a3 = *(const float4*)(aptr + k0 + 12);
#pragma unroll
        for (int pp = 0; pp < 4; ++pp) {
            int idx = pp * 256 + tid;
            int row = idx >> 3, seg = idx & 7;
            const float* wp = W + ((size_t)((g << 9) + n0 + row)) * DIN + k0 + (seg << 3);
            bw0[pp] = *(const float4*)(wp);
            bw1[pp] = *(const float4*)(wp + 4);
        }
    };
    auto swzf = [](int row, int bc) { return (row << 7) + (bc ^ ((row & 7) << 4)); };
    auto write_lds = [&](int buf) {
        char* ab  = smem + buf * 8192;
        char* bb_ = smem + 16384 + buf * 16384;
        s16x8 w0, w1;
        w0[0]=f2b(a0.x); w0[1]=f2b(a0.y); w0[2]=f2b(a0.z); w0[3]=f2b(a0.w);
        w0[4]=f2b(a1.x); w0[5]=f2b(a1.y); w0[6]=f2b(a1.z); w0[7]=f2b(a1.w);
        w1[0]=f2b(a2.x); w1[1]=f2b(a2.y); w1[2]=f2b(a2.z); w1[3]=f2b(a2.w);
        w1[4]=f2b(a3.x); w1[5]=f2b(a3.y); w1[6]=f2b(a3.z); w1[7]=f2b(a3.w);
        const int abase2 = acol << 1;
        *(s16x8*)(ab + swzf(arow, abase2))      = w0;
        *(s16x8*)(ab + swzf(arow, abase2 + 16)) = w1;
#pragma unroll
        for (int pp = 0; pp < 4; ++pp) {
            int idx = pp * 256 + tid;
            int row = idx >> 3, seg = idx & 7;
            s16x8 wvv;
            wvv[0]=f2b(bw0[pp].x); wvv[1]=f2b(bw0[pp].y);
            wvv[2]=f2b(bw0[pp].z); wvv[3]=f2b(bw0[pp].w);
            wvv[4]=f2b(bw1[pp].x); wvv[5]=f2b(bw1[pp].y);
            wvv[6]=f2b(bw1[pp].z); wvv[7]=f2b(bw1[pp].w);
            *(s16x8*)(bb_ + swzf(row, seg << 4)) = wvv;
        }
    };
    f32x4 acc[2][4];
#pragma unroll
    for (int mi = 0; mi < 2; ++mi)
#pragma unroll
        for (int ni = 0; ni < 4; ++ni) acc[mi][ni] = (f32x4){0.f,0.f,0.f,0.f};
    const int colf = lane & 15;
    const int kgrp = lane >> 4;
    auto compute = [&](int buf) {
        const char* ab  = smem + buf * 8192;
        const char* bb_ = smem + 16384 + buf * 16384;
#pragma unroll
        for (int ks = 0; ks < 2; ++ks) {
            const int kb = ks * 64 + kgrp * 16;
            s16x8 af[2], bf[4];
#pragma unroll
            for (int mi = 0; mi < 2; ++mi)
                af[mi] = *(const s16x8*)(ab + swzf(wm * 32 + mi * 16 + colf, kb));
#pragma unroll
            for (int ni = 0; ni < 4; ++ni)
                bf[ni] = *(const s16x8*)(bb_ + swzf(wn * 64 + ni * 16 + colf, kb));
#pragma unroll
            for (int mi = 0; mi < 2; ++mi)
#pragma unroll
                for (int ni = 0; ni < 4; ++ni)
                    acc[mi][ni] = __builtin_amdgcn_mfma_f32_16x16x32_bf16(
                        af[mi], bf[ni], acc[mi][ni], 0, 0, 0);
        }
    };
    load_global(0);
    write_lds(0);
    __syncthreads();
    int buf = 0;
#pragma unroll 1
    for (int kt = 0; kt < 8; ++kt) {
        if (kt < 7) load_global((kt + 1) << 6);
        compute(buf);
        if (kt < 7) write_lds(buf ^ 1);
        __syncthreads();
        buf ^= 1;
    }
    float* cbuf = (float*)smem;
#pragma unroll
    for (int ni = 0; ni < 4; ++ni) {
        const int c = wn * 64 + ni * 16 + colf;
#pragma unroll
        for (int mi = 0; mi < 2; ++mi) {
            const int rr2 = wm * 32 + mi * 16 + kgrp * 4;
            f32x4 v = acc[mi][ni];
            cbuf[(rr2 + 0) * 132 + c] = v[0];
            cbuf[(rr2 + 1) * 132 + c] = v[1];
            cbuf[(rr2 + 2) * 132 + c] = v[2];
            cbuf[(rr2 + 3) * 132 + c] = v[3];
        }
    }
    __syncthreads();
    const int rr = tid >> 5;
    const int cc = (tid & 31) << 2;
    const float4 bvv = *(const float4*)(bias + (g << 9) + n0 + cc);
#pragma unroll
    for (int it = 0; it < 8; ++it) {
        const int row = it * 8 + rr;
        float4 v = *(const float4*)(cbuf + row * 132 + cc);
        float4 o4; o4.x = v.x + bvv.x; o4.y = v.y + bvv.y;
                   o4.z = v.z + bvv.z; o4.w = v.w + bvv.w;
        *(float4*)(out + ((size_t)(bb * TTOT) + t0 + row) * DOUT + n0 + cc) = o4;
    }
}

extern "C" void kernel_launch(void* const* d_in, const int* in_sizes, int n_in,
                              void* d_out, int out_size, void* d_ws, size_t ws_size,
                              hipStream_t stream) {
    const float* x    = (const float*)d_in[0];
    const float* W    = (const float*)d_in[1];
    const float* bias = (const float*)d_in[2];
    float* out = (float*)d_out;

    const size_t wbytes = (size_t)NG * DOUT * DIN * sizeof(ushort);  // 4 MB

    if (ws_size >= wbytes) {
        ushort* wbf = (ushort*)d_ws;
        wconv_kernel<<<1024, 256, 0, stream>>>(W, wbf);
        gemm_kernel<<<NJOB * BATCH * 4, 256, 0, stream>>>(x, wbf, bias, out);
    } else {
        gemm_fallback<<<BATCH * 64 * 4, 256, 0, stream>>>(x, W, bias, out);
    }
}

// Round 13
// 101.397 us; speedup vs baseline: 1.1539x; 1.0111x over previous
//
#include <hip/hip_runtime.h>
#include <hip/hip_bf16.h>
#include <cstdint>

#define BATCH 16
#define TTOT  4096
#define DIN   512
#define DOUT  512
#define NG    8
#define NJOB  33
#define NKT   16     // K tiles of 32

typedef float f32x4 __attribute__((ext_vector_type(4)));
typedef short s16x8 __attribute__((ext_vector_type(8)));

__device__ __forceinline__ short f2b(float f) {
    union { __bf16 b; short s; } u; u.b = (__bf16)f; return u.s;
}

// M-tile jobs per batch (BM=128): 31 full + two 64-row stubs (proven R3/R5).
__device__ __constant__ short JT0[NJOB] = {
    0,128, 256,384,512,640, 768,896,1024,1152,1280,1408, 1536,1664,1792,
    1920,2048,2176,2304,2432, 2560,2688,2816,2944, 3072,3200,3328,3456,
    3584, 3648, 3712,3840,3968};
__device__ __constant__ char JG[NJOB] = {
    0,0, 1,1,1,1, 2,2,2,2,2,2, 3,3,3, 4,4,4,4,4, 5,5,5,5, 6,6,6,6, 6, 7, 7,7,7};
__device__ __constant__ char JBM[NJOB] = {
    127,127, 127,127,127,127, 127,127,127,127,127,127, 127,127,127,
    127,127,127,127,127, 127,127,127,127, 127,127,127,127, 63, 63, 127,127,127};

// ---- Kernel 1: W fp32 -> bf16 slot-swizzled BK=32 image (R11-proven, 0 confl) ----
// chunk c = ((g*4+nt)<<4)|kt, 8KB: img[r<128][slot<4 (16B)] = src k-slot (slot^s(r)),
// s(r)=(r>>1)&3:  k = kt*32 + ((slot^s(r))<<3) + 0..7
__global__ void wconv_kernel(const float* __restrict__ W, ushort* __restrict__ wbf) {
    int gid = blockIdx.x * 256 + threadIdx.x;   // 262144 granules x 16B
    int c = gid >> 9;
    int q = (gid & 511) << 4;
    int r = q >> 6;
    int slot = (q >> 4) & 3;
    int kt = c & 15, nt = (c >> 4) & 3, g = c >> 6;
    int k = (kt << 5) + (((slot ^ ((r >> 1) & 3))) << 3);
    const float* wp = W + ((size_t)((g << 9) + (nt << 7) + r) << 9) + k;
    float4 v0 = *reinterpret_cast<const float4*>(wp);
    float4 v1 = *reinterpret_cast<const float4*>(wp + 4);
    s16x8 o;
    o[0]=f2b(v0.x); o[1]=f2b(v0.y); o[2]=f2b(v0.z); o[3]=f2b(v0.w);
    o[4]=f2b(v1.x); o[5]=f2b(v1.y); o[6]=f2b(v1.z); o[7]=f2b(v1.w);
    *reinterpret_cast<s16x8*>((char*)wbf + (size_t)c * 8192 + q) = o;
}

// ---- Kernel 2: grouped GEMM 128x128x32, 4 waves (2Mx2N), wave 64x64.
// ALL staging via global_load_lds (A raw fp32, B bf16 image); fp32->bf16
// conversion at fragment read. Ring-3 (72KB -> 2 blocks/CU), counted
// vmcnt(6): tile kt+2's 6 DMA ops ride every barrier. ----
__launch_bounds__(256, 2)
__global__ void gemm_kernel(const float* __restrict__ x,
                            const ushort* __restrict__ wbf,
                            const float* __restrict__ bias,
                            float* __restrict__ out) {
    // 3 slots x 24KB: [A fp32 16K][B bf16 8K]; epilogue cbuf overlays slot0.
    __shared__ __align__(16) char smem[73728];

    const int tid  = threadIdx.x;
    const int lane = tid & 63;
    const int wv   = tid >> 6;      // 0..3
    const int wm   = wv >> 1;       // 0..1 : 64-row slab
    const int wn   = wv & 1;        // 0..1 : 64-col slab
    const int colf = lane & 15;
    const int kg   = lane >> 4;

    const int p    = blockIdx.x;
    const int l    = (p & 7) * 264 + (p >> 3);   // XCD-chunked (2112 = 8*264)
    const int nt   = l & 3;                       // nt fastest: x L2/L3 reuse
    const int rest = l >> 2;                      // 0..527
    const int job  = rest >> 4;                   // 0..32
    const int bb   = rest & 15;
    const int t0   = JT0[job];
    const int g    = JG[job];
    const int bmm1 = JBM[job];
    const int n0   = nt << 7;

    const char* bchunk = (const char*)wbf + ((size_t)(((g << 2) + nt) << 4)) * 8192;

    // A DMA source geometry: LDS linear L = i*4096 + tid*16 -> row = i*32 +
    // (tid>>3), 16B-slot = tid&7. LDS slot s holds source k-slot s^(row&7);
    // row&7 = (tid>>3)&7 for all i. Per-i row pointers (stub rows clamped -64,
    // preserving row&7).
    const int srcslot = ((tid & 7) ^ ((tid >> 3) & 7)) << 4;   // byte col in k-tile
    const char* pA0; const char* pA1; const char* pA2; const char* pA3;
    {
        int r0 = (tid >> 3);
        int r1 = 32 + r0, r2 = 64 + r0, r3 = 96 + r0;
        if (r2 > bmm1) r2 -= 64;
        if (r3 > bmm1) r3 -= 64;
        const char* xb = (const char*)(x + ((size_t)(bb * TTOT + t0)) * DIN);
        pA0 = xb + (size_t)r0 * 2048 + srcslot;
        pA1 = xb + (size_t)r1 * 2048 + srcslot;
        pA2 = xb + (size_t)r2 * 2048 + srcslot;
        pA3 = xb + (size_t)r3 * 2048 + srcslot;
    }

#define GLD(SRC_, DST_)                                                     \
    __builtin_amdgcn_global_load_lds(                                       \
        (const __attribute__((address_space(1))) void*)(SRC_),              \
        (__attribute__((address_space(3))) void*)(DST_), 16, 0, 0)

#define STAGE(KT_, SL_) do {                                                \
        char* sb_ = smem + (SL_) * 24576;                                   \
        GLD(pA0 + (KT_) * 128, sb_ + tid * 16);                             \
        GLD(pA1 + (KT_) * 128, sb_ + 4096  + tid * 16);                     \
        GLD(pA2 + (KT_) * 128, sb_ + 8192  + tid * 16);                     \
        GLD(pA3 + (KT_) * 128, sb_ + 12288 + tid * 16);                     \
        const char* bs_ = bchunk + (size_t)(KT_) * 8192 + tid * 16;         \
        GLD(bs_,        sb_ + 16384 + tid * 16);                            \
        GLD(bs_ + 4096, sb_ + 20480 + tid * 16);                            \
    } while (0)

#define COMPUTE(KT_, SL_) do {                                              \
        const char* ab_ = smem + (SL_) * 24576;                             \
        const char* bb_ = ab_ + 16384;                                      \
        __builtin_amdgcn_s_setprio(1);                                      \
        s16x8 bf[4];                                                        \
        _Pragma("unroll")                                                   \
        for (int ni = 0; ni < 4; ++ni) {                                    \
            int r_ = wn * 64 + ni * 16 + colf;                              \
            bf[ni] = *(const s16x8*)(bb_ + (r_ << 6)                        \
                        + ((kg ^ ((r_ >> 1) & 3)) << 4));                   \
        }                                                                   \
        _Pragma("unroll")                                                   \
        for (int mi = 0; mi < 4; ++mi) {                                    \
            int r_ = wm * 64 + mi * 16 + colf;                              \
            const char* base_ = ab_ + (r_ << 7);                            \
            int s0_ = ((kg << 1) ^ (r_ & 7)) << 4;                          \
            int s1_ = (((kg << 1) | 1) ^ (r_ & 7)) << 4;                    \
            f32x4 lo_ = *(const f32x4*)(base_ + s0_);                       \
            f32x4 hi_ = *(const f32x4*)(base_ + s1_);                       \
            s16x8 af_;                                                      \
            af_[0]=f2b(lo_[0]); af_[1]=f2b(lo_[1]);                         \
            af_[2]=f2b(lo_[2]); af_[3]=f2b(lo_[3]);                         \
            af_[4]=f2b(hi_[0]); af_[5]=f2b(hi_[1]);                         \
            af_[6]=f2b(hi_[2]); af_[7]=f2b(hi_[3]);                         \
            _Pragma("unroll")                                               \
            for (int ni = 0; ni < 4; ++ni)                                  \
                acc[mi][ni] = __builtin_amdgcn_mfma_f32_16x16x32_bf16(      \
                    af_, bf[ni], acc[mi][ni], 0, 0, 0);                     \
        }                                                                   \
        __builtin_amdgcn_s_setprio(0);                                      \
    } while (0)

#define FENCE  asm volatile("" ::: "memory")
#define WAITV6 asm volatile("s_waitcnt vmcnt(6)" ::: "memory")
#define WAITV0 asm volatile("s_waitcnt vmcnt(0)" ::: "memory")
#define WAITL0 asm volatile("s_waitcnt lgkmcnt(0)" ::: "memory")
#define BAR    __builtin_amdgcn_s_barrier()

    f32x4 acc[4][4];
#pragma unroll
    for (int mi = 0; mi < 4; ++mi)
#pragma unroll
        for (int ni = 0; ni < 4; ++ni)
            acc[mi][ni] = (f32x4){0.f, 0.f, 0.f, 0.f};

    // ---- prologue: tiles 0,1 staged; tile 0 drained, tile 1 rides ----
    STAGE(0, 0);
    FENCE;
    STAGE(1, 1);
    FENCE;
    WAITV6;
    BAR;

#pragma unroll
    for (int kt = 0; kt < NKT; ++kt) {
        if (kt + 2 < NKT) { STAGE(kt + 2, (kt + 2) % 3); FENCE; }
        COMPUTE(kt, kt % 3);
        if (kt < NKT - 1) {
            if (kt < NKT - 2) { WAITV6; }   // drain tile kt+1; kt+2 rides
            else              { WAITV0; }   // kt==14: only tile 15 left
            BAR;
        }
    }
    BAR;   // all LDS reads done before cbuf overlay

    // ---- epilogue: 4 passes of 32 rows via LDS transpose (stride 132) ----
    float* cbuf = (float*)smem;            // 16.9KB over slot 0
    const int er = tid >> 3;               // 0..31
    const int ec = (tid & 7) << 4;         // 16 f32 per thread
    float4 bvv[4];
#pragma unroll
    for (int i = 0; i < 4; ++i)
        bvv[i] = *(const float4*)(bias + (g << 9) + n0 + ec + (i << 2));

#pragma unroll
    for (int pp = 0; pp < 4; ++pp) {
        if (wm == (pp >> 1)) {
#pragma unroll
            for (int m = 0; m < 2; ++m) {
                const int mi = (pp & 1) * 2 + m;
#pragma unroll
                for (int ni = 0; ni < 4; ++ni) {
                    const int base = (m * 16 + kg * 4) * 132 + wn * 64 + ni * 16 + colf;
                    f32x4 v = acc[mi][ni];
                    cbuf[base]       = v[0];
                    cbuf[base + 132] = v[1];
                    cbuf[base + 264] = v[2];
                    cbuf[base + 396] = v[3];
                }
            }
        }
        WAITL0;
        BAR;
        const int row = pp * 32 + er;
        if (row <= bmm1) {
            float* orow = out + ((size_t)(bb * TTOT + t0 + row)) * DOUT + n0 + ec;
            const float* crow = cbuf + er * 132 + ec;
#pragma unroll
            for (int i = 0; i < 4; ++i) {
                float4 v = *(const float4*)(crow + (i << 2));
                float4 o4;
                o4.x = v.x + bvv[i].x; o4.y = v.y + bvv[i].y;
                o4.z = v.z + bvv[i].z; o4.w = v.w + bvv[i].w;
                *(float4*)(orow + (i << 2)) = o4;
            }
        }
        BAR;
    }
#undef GLD
#undef STAGE
#undef COMPUTE
#undef FENCE
#undef WAITV6
#undef WAITV0
#undef WAITL0
#undef BAR
}

// ---- Fallback (ws too small): R2-style 64x128 kernel, fp32 W path ----
__launch_bounds__(256)
__global__ void gemm_fallback(const float* __restrict__ x,
                              const float* __restrict__ W,
                              const float* __restrict__ bias,
                              float* __restrict__ out) {
    __shared__ __align__(16) char smem[49152];
    const int tid  = threadIdx.x;
    const int lane = tid & 63;
    const int wid  = tid >> 6;
    const int wm   = wid >> 1;
    const int wn   = wid & 1;
    const int p  = blockIdx.x;
    const int l  = ((p & 7) << 9) + (p >> 3);
    const int mt = l >> 2;
    const int nt = l & 3;
    const int bb = mt >> 6;
    const int t0 = (mt & 63) << 6;
    const int n0 = nt << 7;
    int g = 0;
    if (t0 >= 256)  g++; if (t0 >= 768)  g++; if (t0 >= 1536) g++;
    if (t0 >= 1920) g++; if (t0 >= 2560) g++; if (t0 >= 3072) g++;
    if (t0 >= 3648) g++;
    const int arow = tid >> 2;
    const int acol = (tid & 3) << 4;
    const float* aptr = x + ((size_t)(bb * TTOT + t0 + arow)) * DIN + acol;
    float4 a0, a1, a2, a3;
    float4 bw0[4], bw1[4];
    auto load_global = [&](int k0) {
        a0 = *(const float4*)(aptr + k0);
        a1 = *(const float4*)(aptr + k0 + 4);
        a2 = *(const float4*)(aptr + k0 + 8);
        a3 = *(const float4*)(aptr + k0 + 12);
#pragma unroll
        for (int pp = 0; pp < 4; ++pp) {
            int idx = pp * 256 + tid;
            int row = idx >> 3, seg = idx & 7;
            const float* wp = W + ((size_t)((g << 9) + n0 + row)) * DIN + k0 + (seg << 3);
            bw0[pp] = *(const float4*)(wp);
            bw1[pp] = *(const float4*)(wp + 4);
        }
    };
    auto swzf = [](int row, int bc) { return (row << 7) + (bc ^ ((row & 7) << 4)); };
    auto write_lds = [&](int buf) {
        char* ab  = smem + buf * 8192;
        char* bb_ = smem + 16384 + buf * 16384;
        s16x8 w0, w1;
        w0[0]=f2b(a0.x); w0[1]=f2b(a0.y); w0[2]=f2b(a0.z); w0[3]=f2b(a0.w);
        w0[4]=f2b(a1.x); w0[5]=f2b(a1.y); w0[6]=f2b(a1.z); w0[7]=f2b(a1.w);
        w1[0]=f2b(a2.x); w1[1]=f2b(a2.y); w1[2]=f2b(a2.z); w1[3]=f2b(a2.w);
        w1[4]=f2b(a3.x); w1[5]=f2b(a3.y); w1[6]=f2b(a3.z); w1[7]=f2b(a3.w);
        const int abase2 = acol << 1;
        *(s16x8*)(ab + swzf(arow, abase2))      = w0;
        *(s16x8*)(ab + swzf(arow, abase2 + 16)) = w1;
#pragma unroll
        for (int pp = 0; pp < 4; ++pp) {
            int idx = pp * 256 + tid;
            int row = idx >> 3, seg = idx & 7;
            s16x8 wvv;
            wvv[0]=f2b(bw0[pp].x); wvv[1]=f2b(bw0[pp].y);
            wvv[2]=f2b(bw0[pp].z); wvv[3]=f2b(bw0[pp].w);
            wvv[4]=f2b(bw1[pp].x); wvv[5]=f2b(bw1[pp].y);
            wvv[6]=f2b(bw1[pp].z); wvv[7]=f2b(bw1[pp].w);
            *(s16x8*)(bb_ + swzf(row, seg << 4)) = wvv;
        }
    };
    f32x4 acc[2][4];
#pragma unroll
    for (int mi = 0; mi < 2; ++mi)
#pragma unroll
        for (int ni = 0; ni < 4; ++ni) acc[mi][ni] = (f32x4){0.f,0.f,0.f,0.f};
    const int colf = lane & 15;
    const int kgrp = lane >> 4;
    auto compute = [&](int buf) {
        const char* ab  = smem + buf * 8192;
        const char* bb_ = smem + 16384 + buf * 16384;
#pragma unroll
        for (int ks = 0; ks < 2; ++ks) {
            const int kb = ks * 64 + kgrp * 16;
            s16x8 af[2], bf[4];
#pragma unroll
            for (int mi = 0; mi < 2; ++mi)
                af[mi] = *(const s16x8*)(ab + swzf(wm * 32 + mi * 16 + colf, kb));
#pragma unroll
            for (int ni = 0; ni < 4; ++ni)
                bf[ni] = *(const s16x8*)(bb_ + swzf(wn * 64 + ni * 16 + colf, kb));
#pragma unroll
            for (int mi = 0; mi < 2; ++mi)
#pragma unroll
                for (int ni = 0; ni < 4; ++ni)
                    acc[mi][ni] = __builtin_amdgcn_mfma_f32_16x16x32_bf16(
                        af[mi], bf[ni], acc[mi][ni], 0, 0, 0);
        }
    };
    load_global(0);
    write_lds(0);
    __syncthreads();
    int buf = 0;
#pragma unroll 1
    for (int kt = 0; kt < 8; ++kt) {
        if (kt < 7) load_global((kt + 1) << 6);
        compute(buf);
        if (kt < 7) write_lds(buf ^ 1);
        __syncthreads();
        buf ^= 1;
    }
    float* cbuf = (float*)smem;
#pragma unroll
    for (int ni = 0; ni < 4; ++ni) {
        const int c = wn * 64 + ni * 16 + colf;
#pragma unroll
        for (int mi = 0; mi < 2; ++mi) {
            const int rr2 = wm * 32 + mi * 16 + kgrp * 4;
            f32x4 v = acc[mi][ni];
            cbuf[(rr2 + 0) * 132 + c] = v[0];
            cbuf[(rr2 + 1) * 132 + c] = v[1];
            cbuf[(rr2 + 2) * 132 + c] = v[2];
            cbuf[(rr2 + 3) * 132 + c] = v[3];
        }
    }
    __syncthreads();
    const int rr = tid >> 5;
    const int cc = (tid & 31) << 2;
    const float4 bvv = *(const float4*)(bias + (g << 9) + n0 + cc);
#pragma unroll
    for (int it = 0; it < 8; ++it) {
        const int row = it * 8 + rr;
        float4 v = *(const float4*)(cbuf + row * 132 + cc);
        float4 o4; o4.x = v.x + bvv.x; o4.y = v.y + bvv.y;
                   o4.z = v.z + bvv.z; o4.w = v.w + bvv.w;
        *(float4*)(out + ((size_t)(bb * TTOT) + t0 + row) * DOUT + n0 + cc) = o4;
    }
}

extern "C" void kernel_launch(void* const* d_in, const int* in_sizes, int n_in,
                              void* d_out, int out_size, void* d_ws, size_t ws_size,
                              hipStream_t stream) {
    const float* x    = (const float*)d_in[0];
    const float* W    = (const float*)d_in[1];
    const float* bias = (const float*)d_in[2];
    float* out = (float*)d_out;

    const size_t wbytes = (size_t)NG * DOUT * DIN * sizeof(ushort);  // 4 MB

    if (ws_size >= wbytes) {
        ushort* wbf = (ushort*)d_ws;
        wconv_kernel<<<1024, 256, 0, stream>>>(W, wbf);
        gemm_kernel<<<NJOB * BATCH * 4, 256, 0, stream>>>(x, wbf, bias, out);
    } else {
        gemm_fallback<<<BATCH * 64 * 4, 256, 0, stream>>>(x, W, bias, out);
    }
}